// Round 15
// baseline (76.147 us; speedup 1.0000x reference)
//
#include <hip/hip_runtime.h>
#include <math.h>

// Histogram2D, sparse formulation: each point adds its exact-i32 7x7 window
// outer-product qx[i]*qy[j] into a per-block LDS histogram via LDS atomics
// (CU-local). Ladder: R8 dense-MFMA 84.5 -> R17 sparse 81.9 -> R18 halve
// partials 76.4 [MATCHED] -> R20 7x7 window 75.1 [MATCHED: -23% atomics
// -> -1.3us]. Model confirmed twice: hot loop is LDS-ATOMIC-STREAM-bound.
// R19 FAILED (77.9): LDS weight-LUT contends with atomics on same pipe.
// Other FAILED (never revisit): R10 device atomics (+12.7), R11 software
// grid barrier (+150), R12 dense 100%-occupancy (neutral).
// Decomposition: poison fill ~41.1 (fixed floor) + harness/iteration
// residue ~20 + hist ~6-7 + reduce ~3.5.
// R21 (this round): u64 PACKED atomics — 49x ds_add_u32 -> 28x ds_add_u64.
// Pack 7 y-weights into 4 u64 slots over even-aligned 8-bin span
// (eb = by0&~1); per x-row, qi*W[t] (u64 mul) yields a correctly packed
// pair: qi*w <= 15129 and per-block low-half bin sums ~1e5 << 2^31 -> no
// carry into high word, lane-exact. Bit-identical q values -> bit-identical
// output. DISCRIMINATOR: op-issue-limited pipe -> -1.5-3us; bank-limited
// (56 bank-touches vs 49) -> neutral. LDH 129->130 (even, 8B-aligned rows;
// bank=(2r+c)%32 uniform). +35 VALU/pt rides the idle VALU pipe (R19).
// Predicted 75.1 -> 72-73.5 (op-limited, prior 70%) or +-0.5 (bank-ltd).
// absmax exactly 0.0009765625. Numerics: A&S erf, q=rint(w*320), exact
// i32, bf16 partials. LDS 65 KiB -> 1 block/CU, 16 waves.

#define NBINS   128
#define NB2     (NBINS * NBINS)
#define LDH     130               // padded LDS row stride (i32), EVEN for u64
#define THREADS 1024
#define NBLOCKS 256
#define QSCALE  320.0f

static __device__ __forceinline__ unsigned short f2bf(float f) {
    unsigned int b = __float_as_uint(f);
    b += 0x7fff + ((b >> 16) & 1);            // RNE
    return (unsigned short)(b >> 16);
}
static __device__ __forceinline__ float bf2f(unsigned short u) {
    return __uint_as_float((unsigned int)u << 16);
}

// Abramowitz-Stegun 7.1.26: |err| <= 1.5e-7, branch-free.
static __device__ __forceinline__ float erf_fast(float x) {
    const float ax = fabsf(x);
    const float t  = __builtin_amdgcn_rcpf(fmaf(0.3275911f, ax, 1.0f));
    const float e  = __expf(-x * x);          // v_exp_f32; inf^2 -> e=0 safe
    float p = fmaf(1.061405429f, t, -1.453152027f);
    p = fmaf(p, t, 1.421413741f);
    p = fmaf(p, t, -0.284496736f);
    p = fmaf(p, t, 0.254829592f);
    p = p * t;
    return copysignf(fmaf(-p, e, 1.0f), x);
}

// Per-axis 7-bin window: base bin b0 (clamped) + 7 quantized weights.
// Window [floor(spos)-3, floor(spos)+3]: captures every bin with q>=1
// (near edge >= ~2.95 sigma -> mass < 0.5/320 -> q=0; proven R20).
static __device__ __forceinline__ void axis_q(
    float u, float e0, float inv, int& b0, int q[7])
{
    const float cc = 0.7071067811865476f;     // 1/sqrt(2); bw = bin width
    const float spos = (u - e0) * inv;
    int b = (int)floorf(spos) - 3;
    b0 = b < 0 ? 0 : (b > NBINS - 7 ? NBINS - 7 : b);
    const float t0 = ((float)b0 - spos) * cc;
    float z[8];
    #pragma unroll
    for (int k = 0; k < 8; ++k) z[k] = erf_fast(t0 + (float)k * cc);
    #pragma unroll
    for (int k = 0; k < 7; ++k)
        q[k] = (int)rintf(0.5f * (z[k + 1] - z[k]) * QSCALE);
}

__global__ __launch_bounds__(THREADS, 4) void hist_sparse_kernel(
    const float* __restrict__ x,
    const float* __restrict__ edges_x,
    const float* __restrict__ edges_y,
    unsigned short* __restrict__ partials,   // bf16 [block][16384]
    float* __restrict__ btot,                // f32 [256]
    int n)
{
    __shared__ __align__(16) int lh[NBINS * LDH];   // 65 KiB, 8B-aligned rows
    __shared__ int xw[16];

    const int tid  = threadIdx.x;
    const int lane = tid & 63;
    const int wv   = tid >> 6;               // 0..15

    for (int i = tid; i < NBINS * LDH; i += THREADS) lh[i] = 0;

    const float e0x = edges_x[0];
    const float dxw = edges_x[1] - e0x;
    const float e0y = edges_y[0];
    const float dyw = edges_y[1] - e0y;
    const float ivx = 1.0f / dxw;
    const float ivy = 1.0f / dyw;
    __syncthreads();

    int bsum = 0;
    const int stride = gridDim.x * THREADS;
    for (int p = blockIdx.x * THREADS + tid; p < n; p += stride) {
        // both coordinates in one 8B load (p*24 is 8-aligned)
        const float2 u = *(const float2*)(x + (size_t)p * 6);
        int bx0, by0, qx[7], qy[7];
        axis_q(u.x, e0x, ivx, bx0, qx);
        axis_q(u.y, e0y, ivy, by0, qy);

        int sx = 0, sy = 0;
        #pragma unroll
        for (int k = 0; k < 7; ++k) { sx += qx[k]; sy += qy[k]; }
        bsum += sx * sy;                     // exact; all bins in-range post-clamp

        // pack 7 y-weights into 4 u64 slots over even-aligned span
        // slots eb..eb+7; window occupies slots sh..sh+6 (sh = by0&1)
        const int eb = by0 & ~1;
        unsigned long long W[4];
        if ((by0 & 1) == 0) {
            W[0] = (unsigned int)qy[0] | ((unsigned long long)qy[1] << 32);
            W[1] = (unsigned int)qy[2] | ((unsigned long long)qy[3] << 32);
            W[2] = (unsigned int)qy[4] | ((unsigned long long)qy[5] << 32);
            W[3] = (unsigned int)qy[6];
        } else {
            W[0] = ((unsigned long long)qy[0] << 32);
            W[1] = (unsigned int)qy[1] | ((unsigned long long)qy[2] << 32);
            W[2] = (unsigned int)qy[3] | ((unsigned long long)qy[4] << 32);
            W[3] = (unsigned int)qy[5] | ((unsigned long long)qy[6] << 32);
        }

        unsigned long long* const base =
            (unsigned long long*)(lh + bx0 * LDH + eb);
        #pragma unroll
        for (int i = 0; i < 7; ++i) {
            const unsigned long long qi = (unsigned int)qx[i];
            unsigned long long* const rowp = base + i * (LDH / 2);
            #pragma unroll
            for (int t = 0; t < 4; ++t)
                atomicAdd(rowp + t, qi * W[t]);
        }
    }
    __syncthreads();

    // epilogue: LDS i32 -> bf16 partials. Thread t: 16 consecutive bins
    // (32B contiguous global store as 4x ushort4); c+3 never crosses a row.
    {
        const float qs = 1.0f / (QSCALE * QSCALE);
        unsigned short* my = partials + (size_t)blockIdx.x * NB2;
        #pragma unroll
        for (int v = 0; v < 4; ++v) {
            const int e = tid * 16 + v * 4;
            const int r = e >> 7;
            const int c = e & 127;
            const int* row = lh + r * LDH + c;
            ushort4 o;
            o.x = f2bf((float)row[0] * qs);
            o.y = f2bf((float)row[1] * qs);
            o.z = f2bf((float)row[2] * qs);
            o.w = f2bf((float)row[3] * qs);
            *(ushort4*)(my + e) = o;
        }
    }

    // block total (exact i32 within wave; block sum ~2e8 << 2^31)
    #pragma unroll
    for (int off = 32; off > 0; off >>= 1) bsum += __shfl_down(bsum, off, 64);
    if (lane == 0) xw[wv] = bsum;
    __syncthreads();
    if (tid == 0) {
        const float qs = 1.0f / (QSCALE * QSCALE);
        int s = 0;
        #pragma unroll
        for (int k = 0; k < 16; ++k) s += xw[k];
        btot[blockIdx.x] = (float)s * qs;
    }
}

// Fused reduction + normalize: 256 blocks x 256 threads (measured-good).
// Block B covers bins [B*64, B*64+64). Thread t: bin4 = t&15 (4 bins),
// pgroup = t>>4 (16 partials each, of 256 total).
__global__ void reduce_kernel(const unsigned short* __restrict__ partials,
                              const float* __restrict__ btot,
                              const float* __restrict__ edges_x,
                              const float* __restrict__ edges_y,
                              float* __restrict__ out)
{
    __shared__ float4 red[16][16];
    __shared__ float ws[4];
    __shared__ float stot;

    const int t = threadIdx.x;
    const int bin4 = t & 15;
    const int pg = t >> 4;
    const int binBase = blockIdx.x * 64;

    // grand total (redundant per block; btot is 1KB, L2-hot)
    float tl = btot[t];
    #pragma unroll
    for (int off = 32; off > 0; off >>= 1) tl += __shfl_down(tl, off, 64);
    if ((t & 63) == 0) ws[t >> 6] = tl;

    // sum 16 partials for 4 bins
    const unsigned short* p =
        partials + (size_t)(pg * 16) * NB2 + binBase + bin4 * 4;
    float4 s = {0.f, 0.f, 0.f, 0.f};
    #pragma unroll 8
    for (int k = 0; k < 16; ++k) {
        const ushort4 v = *(const ushort4*)(p + (size_t)k * NB2);
        s.x += bf2f(v.x); s.y += bf2f(v.y); s.z += bf2f(v.z); s.w += bf2f(v.w);
    }
    red[pg][bin4] = s;
    __syncthreads();

    if (t == 0) {
        const float dxw = edges_x[1] - edges_x[0];
        const float dyw = edges_y[1] - edges_y[0];
        stot = 1.0f / ((ws[0] + ws[1] + ws[2] + ws[3]) * dxw * dyw);
    }
    __syncthreads();

    if (t < 16) {
        float4 a = red[0][t];
        #pragma unroll
        for (int g = 1; g < 16; ++g) {
            const float4 b = red[g][t];
            a.x += b.x; a.y += b.y; a.z += b.z; a.w += b.w;
        }
        a.x *= stot; a.y *= stot; a.z *= stot; a.w *= stot;
        *(float4*)(out + binBase + t * 4) = a;
    }
}

extern "C" void kernel_launch(void* const* d_in, const int* in_sizes, int n_in,
                              void* d_out, int out_size, void* d_ws, size_t ws_size,
                              hipStream_t stream)
{
    const float* x  = (const float*)d_in[0];
    const float* ex = (const float*)d_in[1];
    const float* ey = (const float*)d_in[2];
    float* out = (float*)d_out;
    const int n = in_sizes[0] / 6;

    unsigned short* partials = (unsigned short*)d_ws;             // 256*16384 bf16
    float* btot = (float*)((char*)d_ws + (size_t)NBLOCKS * NB2 * 2);  // 256 f32

    hist_sparse_kernel<<<NBLOCKS, THREADS, 0, stream>>>(x, ex, ey, partials, btot, n);
    reduce_kernel<<<NB2 / 64, 256, 0, stream>>>(partials, btot, ex, ey, out);
}

// Round 18
// 75.725 us; speedup vs baseline: 1.0056x; 1.0056x over previous
//
#include <hip/hip_runtime.h>
#include <math.h>

// Histogram2D, sparse formulation: each point adds its exact-i32 7x7 window
// outer-product qx[i]*qy[j] into a per-block LDS histogram via LDS atomics
// (CU-local). Ladder: R8 dense-MFMA 84.5 -> R17 sparse 81.9 -> R18 halve
// partials 76.4 [MATCHED] -> R20 7x7 window 75.1 [MATCHED] -> R21 u64
// packed atomics 76.1 FAILED (+1.0). Discriminator result: atomic stream is
// BANK-TOUCH-bound — halving instruction count (same bank touches) lost.
// R19 FAILED (77.9): LDS LUT contends with atomics (erf/VALU NOT critical).
// Other FAILED (never revisit): R10 device atomics (+12.7), R11 software
// grid barrier (+150), R12 dense 100%-occupancy (neutral).
// Decomposition (revised): fill ~41.2 (fixed) + harness reset() tiny-
// dispatch floor ~20 (rocprof.md: dozens of memset/restores per iter) +
// hist ~6-8 (atomics ~5; 7x7 minimal per R20 proof) + reduce ~4-5 + gaps.
// R22: revert hist to R20 exactly; single change = reduce kernel TLP:
// 256->512 blocks (8 waves/CU, 32 bins/block, load chain 16->8). Same
// 8 MiB traffic; pure latency-hiding. R23/R24: resubmit unchanged (R22
// benches failed on acquisition; no data). Predicted 75.1 -> 72.6-74.1;
// absmax exactly 0.0009765625. If neutral: controllable budget exhausted
// -> declare floor next round.
// Numerics: A&S erf, q=rint(w*320) (max ~123), exact i32, bf16 partials.
// LDS hist stride 129 i32 -> bank ~(bx+by+c)%32 uniform; 64.5 KiB ->
// 1 block/CU, 16 waves. All 49 atomic offsets compile-time imm.

#define NBINS   128
#define NB2     (NBINS * NBINS)
#define LDH     129               // padded LDS row stride (i32)
#define THREADS 1024
#define NBLOCKS 256
#define QSCALE  320.0f

static __device__ __forceinline__ unsigned short f2bf(float f) {
    unsigned int b = __float_as_uint(f);
    b += 0x7fff + ((b >> 16) & 1);            // RNE
    return (unsigned short)(b >> 16);
}
static __device__ __forceinline__ float bf2f(unsigned short u) {
    return __uint_as_float((unsigned int)u << 16);
}

// Abramowitz-Stegun 7.1.26: |err| <= 1.5e-7, branch-free.
static __device__ __forceinline__ float erf_fast(float x) {
    const float ax = fabsf(x);
    const float t  = __builtin_amdgcn_rcpf(fmaf(0.3275911f, ax, 1.0f));
    const float e  = __expf(-x * x);          // v_exp_f32; inf^2 -> e=0 safe
    float p = fmaf(1.061405429f, t, -1.453152027f);
    p = fmaf(p, t, 1.421413741f);
    p = fmaf(p, t, -0.284496736f);
    p = fmaf(p, t, 0.254829592f);
    p = p * t;
    return copysignf(fmaf(-p, e, 1.0f), x);
}

// Per-axis 7-bin window: base bin b0 (clamped) + 7 quantized weights.
// Window [floor(spos)-3, floor(spos)+3]: captures every bin with q>=1
// (near edge >= ~2.95 sigma -> mass < 0.5/320 -> q=0; proven R20).
static __device__ __forceinline__ void axis_q(
    float u, float e0, float inv, int& b0, int q[7])
{
    const float cc = 0.7071067811865476f;     // 1/sqrt(2); bw = bin width
    const float spos = (u - e0) * inv;
    int b = (int)floorf(spos) - 3;
    b0 = b < 0 ? 0 : (b > NBINS - 7 ? NBINS - 7 : b);
    const float t0 = ((float)b0 - spos) * cc;
    float z[8];
    #pragma unroll
    for (int k = 0; k < 8; ++k) z[k] = erf_fast(t0 + (float)k * cc);
    #pragma unroll
    for (int k = 0; k < 7; ++k)
        q[k] = (int)rintf(0.5f * (z[k + 1] - z[k]) * QSCALE);
}

__global__ __launch_bounds__(THREADS, 4) void hist_sparse_kernel(
    const float* __restrict__ x,
    const float* __restrict__ edges_x,
    const float* __restrict__ edges_y,
    unsigned short* __restrict__ partials,   // bf16 [block][16384]
    float* __restrict__ btot,                // f32 [256]
    int n)
{
    __shared__ int lh[NBINS * LDH];          // 64.5 KiB
    __shared__ int xw[16];

    const int tid  = threadIdx.x;
    const int lane = tid & 63;
    const int wv   = tid >> 6;               // 0..15

    for (int i = tid; i < NBINS * LDH; i += THREADS) lh[i] = 0;

    const float e0x = edges_x[0];
    const float dxw = edges_x[1] - e0x;
    const float e0y = edges_y[0];
    const float dyw = edges_y[1] - e0y;
    const float ivx = 1.0f / dxw;
    const float ivy = 1.0f / dyw;
    __syncthreads();

    int bsum = 0;
    const int stride = gridDim.x * THREADS;
    for (int p = blockIdx.x * THREADS + tid; p < n; p += stride) {
        // both coordinates in one 8B load (p*24 is 8-aligned)
        const float2 u = *(const float2*)(x + (size_t)p * 6);
        int bx0, by0, qx[7], qy[7];
        axis_q(u.x, e0x, ivx, bx0, qx);
        axis_q(u.y, e0y, ivy, by0, qy);

        int sx = 0, sy = 0;
        #pragma unroll
        for (int k = 0; k < 7; ++k) { sx += qx[k]; sy += qy[k]; }
        bsum += sx * sy;                     // exact; all bins in-range post-clamp

        int* const base = lh + bx0 * LDH + by0;
        #pragma unroll
        for (int i = 0; i < 7; ++i) {
            const int qi = qx[i];
            #pragma unroll
            for (int j = 0; j < 7; ++j)
                atomicAdd(base + i * LDH + j, qi * qy[j]);
        }
    }
    __syncthreads();

    // epilogue: LDS i32 -> bf16 partials. Thread t: 16 consecutive bins
    // (32B contiguous global store as 4x ushort4); c+3 never crosses a row.
    {
        const float qs = 1.0f / (QSCALE * QSCALE);
        unsigned short* my = partials + (size_t)blockIdx.x * NB2;
        #pragma unroll
        for (int v = 0; v < 4; ++v) {
            const int e = tid * 16 + v * 4;
            const int r = e >> 7;
            const int c = e & 127;
            const int* row = lh + r * LDH + c;
            ushort4 o;
            o.x = f2bf((float)row[0] * qs);
            o.y = f2bf((float)row[1] * qs);
            o.z = f2bf((float)row[2] * qs);
            o.w = f2bf((float)row[3] * qs);
            *(ushort4*)(my + e) = o;
        }
    }

    // block total (exact i32 within wave; block sum ~2e8 << 2^31)
    #pragma unroll
    for (int off = 32; off > 0; off >>= 1) bsum += __shfl_down(bsum, off, 64);
    if (lane == 0) xw[wv] = bsum;
    __syncthreads();
    if (tid == 0) {
        const float qs = 1.0f / (QSCALE * QSCALE);
        int s = 0;
        #pragma unroll
        for (int k = 0; k < 16; ++k) s += xw[k];
        btot[blockIdx.x] = (float)s * qs;
    }
}

// Fused reduction + normalize: R22 = 512 blocks x 256 threads (8 waves/CU,
// was 4). Block B covers bins [B*32, B*32+32). Thread t: bin4 = t&7
// (4 bins), pgroup = t>>3 (8 partials each, of 256 total) — chain 16->8.
__global__ void reduce_kernel(const unsigned short* __restrict__ partials,
                              const float* __restrict__ btot,
                              const float* __restrict__ edges_x,
                              const float* __restrict__ edges_y,
                              float* __restrict__ out)
{
    __shared__ float4 red[32][8];
    __shared__ float ws[4];
    __shared__ float stot;

    const int t = threadIdx.x;
    const int bin4 = t & 7;
    const int pg = t >> 3;
    const int binBase = blockIdx.x * 32;

    // grand total (redundant per block; btot is 1KB, L2-hot)
    float tl = btot[t];
    #pragma unroll
    for (int off = 32; off > 0; off >>= 1) tl += __shfl_down(tl, off, 64);
    if ((t & 63) == 0) ws[t >> 6] = tl;

    // sum 8 partials for 4 bins
    const unsigned short* p =
        partials + (size_t)(pg * 8) * NB2 + binBase + bin4 * 4;
    float4 s = {0.f, 0.f, 0.f, 0.f};
    #pragma unroll
    for (int k = 0; k < 8; ++k) {
        const ushort4 v = *(const ushort4*)(p + (size_t)k * NB2);
        s.x += bf2f(v.x); s.y += bf2f(v.y); s.z += bf2f(v.z); s.w += bf2f(v.w);
    }
    red[pg][bin4] = s;
    __syncthreads();

    if (t == 0) {
        const float dxw = edges_x[1] - edges_x[0];
        const float dyw = edges_y[1] - edges_y[0];
        stot = 1.0f / ((ws[0] + ws[1] + ws[2] + ws[3]) * dxw * dyw);
    }
    __syncthreads();

    if (t < 8) {
        float4 a = red[0][t];
        #pragma unroll
        for (int g = 1; g < 32; ++g) {
            const float4 b = red[g][t];
            a.x += b.x; a.y += b.y; a.z += b.z; a.w += b.w;
        }
        a.x *= stot; a.y *= stot; a.z *= stot; a.w *= stot;
        *(float4*)(out + binBase + t * 4) = a;
    }
}

extern "C" void kernel_launch(void* const* d_in, const int* in_sizes, int n_in,
                              void* d_out, int out_size, void* d_ws, size_t ws_size,
                              hipStream_t stream)
{
    const float* x  = (const float*)d_in[0];
    const float* ex = (const float*)d_in[1];
    const float* ey = (const float*)d_in[2];
    float* out = (float*)d_out;
    const int n = in_sizes[0] / 6;

    unsigned short* partials = (unsigned short*)d_ws;             // 256*16384 bf16
    float* btot = (float*)((char*)d_ws + (size_t)NBLOCKS * NB2 * 2);  // 256 f32

    hist_sparse_kernel<<<NBLOCKS, THREADS, 0, stream>>>(x, ex, ey, partials, btot, n);
    reduce_kernel<<<NB2 / 32, 256, 0, stream>>>(partials, btot, ex, ey, out);
}